// Round 3
// baseline (12690.257 us; speedup 1.0000x reference)
//
#include <hip/hip_runtime.h>
#include <cstdint>
#include <cstddef>

// Problem constants
#define T_STEPS 12
#define N_NODES 4096
#define F_INP   64
#define H_G     128
#define H_L     128
#define N_CLS   10
#define N_EDGES 65536
#define NSEQ    N_NODES          // LSTM scan length (over nodes!)
#define NB      T_STEPS          // LSTM batch (the 12 time slices)
#define G4      (4 * H_L)        // 512 gate columns
#define CHUNK   1024             // scan steps per chunk
#define NCHUNK  (NSEQ / CHUNK)

typedef float v2f __attribute__((ext_vector_type(2)));

__device__ __forceinline__ float sigmoidf_(float x) { return 1.0f / (1.0f + expf(-x)); }
// fast sigmoid: v_exp_f32 (exp2) + v_rcp_f32; rel err ~1e-7, fine vs 1.76e-6 budget
__device__ __forceinline__ float fsigmoid_(float x) {
    float e = __builtin_amdgcn_exp2f(-1.44269504f * x);
    return __builtin_amdgcn_rcpf(1.0f + e);
}
__device__ __forceinline__ float geluf_(float x) { return 0.5f * x * (1.0f + erff(x * 0.70710678f)); }

// ---------------- graph preprocessing ----------------

__global__ void k_deg_cnt(const int* __restrict__ row, const int* __restrict__ col,
                          const float* __restrict__ w,
                          float* __restrict__ deg, int* __restrict__ cnt) {
    int i = blockIdx.x * 256 + threadIdx.x;
    if (i < N_EDGES) {
        int d = col[i];
        atomicAdd(&deg[d], w[i]);
        atomicAdd(&cnt[d], 1);
    } else if (i < N_EDGES + N_NODES) {
        int n = i - N_EDGES;
        atomicAdd(&deg[n], 1.0f);
        atomicAdd(&cnt[n], 1);
    }
}

__global__ void k_dinv(const float* __restrict__ deg, float* __restrict__ dinv) {
    int n = blockIdx.x * 256 + threadIdx.x;
    if (n < N_NODES) {
        float d = deg[n];
        dinv[n] = d > 0.0f ? rsqrtf(d) : 0.0f;
    }
}

__global__ void k_scan(int* cnt, int* __restrict__ row_ptr) {
    __shared__ int s[1024];
    int tid = threadIdx.x;
    int4 v = ((const int4*)cnt)[tid];
    int local = v.x + v.y + v.z + v.w;
    s[tid] = local;
    __syncthreads();
    for (int off = 1; off < 1024; off <<= 1) {
        int val = (tid >= off) ? s[tid - off] : 0;
        __syncthreads();
        s[tid] += val;
        __syncthreads();
    }
    int base = s[tid] - local;
    int4 o;
    o.x = base;
    o.y = o.x + v.x;
    o.z = o.y + v.y;
    o.w = o.z + v.z;
    ((int4*)row_ptr)[tid] = o;
    ((int4*)cnt)[tid] = o;
    if (tid == 1023) row_ptr[4096] = base + local;
}

__global__ void k_scatter(const int* __restrict__ row, const int* __restrict__ col,
                          const float* __restrict__ w, const float* __restrict__ dinv,
                          int* cursor, int* __restrict__ csr_src, float* __restrict__ csr_w) {
    int i = blockIdx.x * 256 + threadIdx.x;
    if (i < N_EDGES) {
        int d = col[i], sy = row[i];
        int pos = atomicAdd(&cursor[d], 1);
        csr_src[pos] = sy;
        csr_w[pos] = dinv[sy] * w[i] * dinv[d];
    } else if (i < N_EDGES + N_NODES) {
        int n = i - N_EDGES;
        int pos = atomicAdd(&cursor[n], 1);
        csr_src[pos] = n;
        float dv = dinv[n];
        csr_w[pos] = dv * dv;
    }
}

// transpose 2x (512,128) -> (128,512): WihT for both LSTM layers
__global__ void k_transpose2(const float* __restrict__ A0, const float* __restrict__ A1,
                             float* __restrict__ out) {
    int i = blockIdx.x * 256 + threadIdx.x;  // 0 .. 131071
    int m = i >> 16;
    int r = i & 65535;
    int k = r >> 9;
    int j = r & 511;
    const float* A = m ? A1 : A0;
    out[m * 65536 + k * 512 + j] = A[j * 128 + k];
}

// ---------------- fp32 GEMM: C[M,128] = A[M,K] @ B[K,128]  (GCN) ----------------
template <int K>
__global__ __launch_bounds__(256) void k_gemm(const float* __restrict__ A,
                                              const float* __restrict__ B,
                                              float* __restrict__ C) {
    constexpr int KP = K + 4;
    __shared__ float sA[64 * KP];
    int tid = threadIdx.x;
    size_t m0 = (size_t)blockIdx.x * 64;
    constexpr int KC = K / 4;
    for (int task = tid; task < 64 * KC; task += 256) {
        int rr = task / KC, kc = task - rr * KC;
        float4 v = *(const float4*)(A + (m0 + rr) * K + kc * 4);
        *(float4*)&sA[rr * KP + kc * 4] = v;
    }
    __syncthreads();
    int tn = tid & 31;
    int tm = tid >> 5;
    float acc[8][4];
#pragma unroll
    for (int r = 0; r < 8; r++)
#pragma unroll
        for (int j = 0; j < 4; j++) acc[r][j] = 0.0f;

    for (int k = 0; k < K; k += 4) {
        float4 b0 = *(const float4*)(B + (size_t)(k + 0) * H_G + tn * 4);
        float4 b1 = *(const float4*)(B + (size_t)(k + 1) * H_G + tn * 4);
        float4 b2 = *(const float4*)(B + (size_t)(k + 2) * H_G + tn * 4);
        float4 b3 = *(const float4*)(B + (size_t)(k + 3) * H_G + tn * 4);
#pragma unroll
        for (int r = 0; r < 8; r++) {
            float4 a = *(const float4*)&sA[(tm * 8 + r) * KP + k];
            acc[r][0] += a.x * b0.x + a.y * b1.x + a.z * b2.x + a.w * b3.x;
            acc[r][1] += a.x * b0.y + a.y * b1.y + a.z * b2.y + a.w * b3.y;
            acc[r][2] += a.x * b0.z + a.y * b1.z + a.z * b2.z + a.w * b3.z;
            acc[r][3] += a.x * b0.w + a.y * b1.w + a.z * b2.w + a.w * b3.w;
        }
    }
#pragma unroll
    for (int r = 0; r < 8; r++) {
        float4 st = make_float4(acc[r][0], acc[r][1], acc[r][2], acc[r][3]);
        *(float4*)(C + (m0 + tm * 8 + r) * H_G + tn * 4) = st;
    }
}

// ---------------- CSR aggregation + bias + exact GELU ----------------
__global__ __launch_bounds__(256) void k_agg(const float* __restrict__ hw,
                                             const int* __restrict__ row_ptr,
                                             const int* __restrict__ csr_src,
                                             const float* __restrict__ csr_w,
                                             const float* __restrict__ bias,
                                             float* __restrict__ out) {
    int f4 = threadIdx.x & 31;
    int nsub = threadIdx.x >> 5;
    int n = blockIdx.x * 8 + nsub;
    int t = blockIdx.y;
    const float* base = hw + (size_t)t * N_NODES * H_G;
    float4 acc = make_float4(0.f, 0.f, 0.f, 0.f);
    int e0 = row_ptr[n], e1 = row_ptr[n + 1];
    for (int e = e0; e < e1; e++) {
        int s = csr_src[e];
        float wv = csr_w[e];
        float4 v = *(const float4*)(base + (size_t)s * H_G + f4 * 4);
        acc.x += wv * v.x;
        acc.y += wv * v.y;
        acc.z += wv * v.z;
        acc.w += wv * v.w;
    }
    float4 b = *(const float4*)(bias + f4 * 4);
    float4 o;
    o.x = geluf_(acc.x + b.x);
    o.y = geluf_(acc.y + b.y);
    o.z = geluf_(acc.z + b.z);
    o.w = geluf_(acc.w + b.w);
    *(float4*)(out + ((size_t)t * N_NODES + n) * H_G + f4 * 4) = o;
}

// ---------------- P = x_seq @ WihT + (bih+bhh), one chunk of scan rows ----------------
__global__ __launch_bounds__(512) void k_gemm_p(const float* __restrict__ A,
                                                const float* __restrict__ BT,
                                                const float* __restrict__ bih,
                                                const float* __restrict__ bhh,
                                                float* __restrict__ Pout,
                                                int r_base, int mode) {
    __shared__ float sA[64 * 128];
    int tid = threadIdx.x;
    int r0 = r_base + blockIdx.x * 64;
    for (int task = tid; task < 64 * 32; task += 512) {
        int rr = task >> 5, kc = task & 31;
        int r = r0 + rr;
        int arow = (mode == 0) ? ((r % 12) * N_NODES + r / 12) : r;
        *(float4*)&sA[rr * 128 + kc * 4] = *(const float4*)(A + (size_t)arow * 128 + kc * 4);
    }
    __syncthreads();
    int jc = tid & 127;
    int rg = tid >> 7;
    float acc[16][4];
#pragma unroll
    for (int rr = 0; rr < 16; rr++)
#pragma unroll
        for (int j = 0; j < 4; j++) acc[rr][j] = 0.f;

    for (int k = 0; k < 128; k += 4) {
        float4 b0 = *(const float4*)(BT + (size_t)(k + 0) * G4 + jc * 4);
        float4 b1 = *(const float4*)(BT + (size_t)(k + 1) * G4 + jc * 4);
        float4 b2 = *(const float4*)(BT + (size_t)(k + 2) * G4 + jc * 4);
        float4 b3 = *(const float4*)(BT + (size_t)(k + 3) * G4 + jc * 4);
#pragma unroll
        for (int rr = 0; rr < 16; rr++) {
            float4 a = *(const float4*)&sA[(rg * 16 + rr) * 128 + k];
            acc[rr][0] += a.x * b0.x + a.y * b1.x + a.z * b2.x + a.w * b3.x;
            acc[rr][1] += a.x * b0.y + a.y * b1.y + a.z * b2.y + a.w * b3.y;
            acc[rr][2] += a.x * b0.z + a.y * b1.z + a.z * b2.z + a.w * b3.z;
            acc[rr][3] += a.x * b0.w + a.y * b1.w + a.z * b2.w + a.w * b3.w;
        }
    }
    float bx = bih[jc * 4 + 0] + bhh[jc * 4 + 0];
    float by = bih[jc * 4 + 1] + bhh[jc * 4 + 1];
    float bz = bih[jc * 4 + 2] + bhh[jc * 4 + 2];
    float bw = bih[jc * 4 + 3] + bhh[jc * 4 + 3];
#pragma unroll
    for (int rr = 0; rr < 16; rr++) {
        int lrow = r0 - r_base + rg * 16 + rr;
        float4 st = make_float4(acc[rr][0] + bx, acc[rr][1] + by, acc[rr][2] + bz, acc[rr][3] + bw);
        *(float4*)(Pout + (size_t)lrow * G4 + jc * 4) = st;
    }
}

// ---------------- sequential LSTM recurrence over one chunk ----------------
// 12 blocks (one per batch element b). 256 threads (4 waves = 1 wave/SIMD); thread
// tid owns gate columns {tid, tid+256}: 2x128 fp32 Whh weights in VGPRs (256 regs,
// allowed by __launch_bounds__(256,1) -> up to 512 VGPR/wave, no spill).
// h broadcast from LDS: 32 wave-uniform ds_read_b128 per wave per step (128/CU,
// half of the round-2 layout). Gate dot products use float2 vector FMAs
// (v_pk_fma_f32, 2 MAC/lane/instr), 4 independent chains to cover FMA latency.
__global__ __launch_bounds__(256, 1) void k_rec(const float* __restrict__ P,
                                                const float* __restrict__ Whh,
                                                float* __restrict__ state,
                                                float* __restrict__ Hout,
                                                int n0, int wmode) {
    __shared__ float sh[H_L];     // h_prev
    __shared__ float gact[G4];    // activated gates
    int tid = threadIdx.x;
    int b = blockIdx.x;
    int j0 = tid;         // gate col (always i/f region: 0..255 -> sigmoid)
    int j1 = tid + 256;   // gate col (256..383 tanh, 384..511 sigmoid)

    // weights in registers: 2 rows x 128 = 256 VGPRs
    v2f w0[64], w1[64];
    const v2f* wr0 = (const v2f*)(Whh + (size_t)j0 * 128);
    const v2f* wr1 = (const v2f*)(Whh + (size_t)j1 * 128);
#pragma unroll
    for (int k = 0; k < 64; k++) w0[k] = wr0[k];
#pragma unroll
    for (int k = 0; k < 64; k++) w1[k] = wr1[k];

    float c = 0.f;
    if (tid < H_L) {
        sh[tid] = state[b * 256 + tid];
        c = state[b * 256 + 128 + tid];
    }
    // prefetch step-0 P values
    float p0n = P[(size_t)b * G4 + j0];
    float p1n = P[(size_t)b * G4 + j1];
    __syncthreads();

    bool j1_tanh = (j1 < 384);

    for (int i = 0; i < CHUNK; i++) {
        float p0 = p0n, p1 = p1n;
        int inx = (i + 1 < CHUNK) ? (i + 1) : i;
        p0n = P[((size_t)inx * NB + b) * G4 + j0];
        p1n = P[((size_t)inx * NB + b) * G4 + j1];

        v2f a0a = {0.f, 0.f}, a0b = {0.f, 0.f}, a1a = {0.f, 0.f}, a1b = {0.f, 0.f};
#pragma unroll
        for (int k = 0; k < 64; k += 2) {
            float4 hv = *(const float4*)&sh[k * 2];   // wave-uniform broadcast
            v2f ha = {hv.x, hv.y};
            v2f hb = {hv.z, hv.w};
            a0a += w0[k] * ha;
            a0b += w0[k + 1] * hb;
            a1a += w1[k] * ha;
            a1b += w1[k + 1] * hb;
        }
        v2f s0 = a0a + a0b;
        v2f s1 = a1a + a1b;
        float g0 = p0 + s0.x + s0.y;
        float g1 = p1 + s1.x + s1.y;

        gact[j0] = fsigmoid_(g0);
        gact[j1] = j1_tanh ? tanhf(g1) : fsigmoid_(g1);
        __syncthreads();

        if (tid < H_L) {
            c = gact[H_L + tid] * c + gact[tid] * gact[2 * H_L + tid];
            float hval = gact[3 * H_L + tid] * tanhf(c);
            sh[tid] = hval;
            if (wmode == 0)
                Hout[((size_t)(n0 + i) * NB + b) * H_L + tid] = hval;
            else if (b == NB - 1)
                Hout[(size_t)(n0 + i) * H_L + tid] = hval;
        }
        __syncthreads();
    }

    if (tid < H_L) {
        state[b * 256 + tid] = sh[tid];
        state[b * 256 + 128 + tid] = c;
    }
}

// ---------------- final FC: out[n,c] = hlast[n,:] . Wfc[c,:] + bfc[c] ----------------
__global__ __launch_bounds__(256) void k_fc(const float* __restrict__ Hlast,
                                            const float* __restrict__ Wfc,
                                            const float* __restrict__ bfc,
                                            float* __restrict__ out) {
    int flat = blockIdx.x * 256 + threadIdx.x;
    int n = flat >> 4, cc = flat & 15;
    if (cc < N_CLS) {
        const float* h = Hlast + (size_t)n * H_L;
        const float* wr = Wfc + (size_t)cc * H_L;
        float acc = bfc[cc];
        for (int k = 0; k < 128; k += 4) {
            float4 hvv = *(const float4*)(h + k);
            float4 wv = *(const float4*)(wr + k);
            acc += hvv.x * wv.x + hvv.y * wv.y + hvv.z * wv.z + hvv.w * wv.w;
        }
        out[n * N_CLS + cc] = acc;
    }
}

extern "C" void kernel_launch(void* const* d_in, const int* in_sizes, int n_in,
                              void* d_out, int out_size, void* d_ws, size_t ws_size,
                              hipStream_t stream) {
    const float* x = (const float*)d_in[0];
    const int* eidx = (const int*)d_in[1];
    const int* erow = eidx;
    const int* ecol = eidx + N_EDGES;
    const float* ew = (const float*)d_in[2];
    const float* W1 = (const float*)d_in[3];
    const float* b1 = (const float*)d_in[4];
    const float* W2 = (const float*)d_in[5];
    const float* b2 = (const float*)d_in[6];
    const float* W3 = (const float*)d_in[7];
    const float* b3 = (const float*)d_in[8];
    const float* Wih1 = (const float*)d_in[9];
    const float* Whh1 = (const float*)d_in[10];
    const float* bih1 = (const float*)d_in[11];
    const float* bhh1 = (const float*)d_in[12];
    const float* Wih2 = (const float*)d_in[13];
    const float* Whh2 = (const float*)d_in[14];
    const float* bih2 = (const float*)d_in[15];
    const float* bhh2 = (const float*)d_in[16];
    const float* Wfc = (const float*)d_in[17];
    const float* bfc = (const float*)d_in[18];
    float* out = (float*)d_out;

    char* p = (char*)d_ws;
    auto alloc = [&](size_t bytes) -> char* {
        char* r = p;
        p += (bytes + 255) & ~(size_t)255;
        return r;
    };
    float* deg = (float*)alloc(N_NODES * 4);  // adjacent to cnt (single memset)
    int* cnt = (int*)alloc(N_NODES * 4);
    float* dinv = (float*)alloc(N_NODES * 4);
    int* row_ptr = (int*)alloc((N_NODES + 1) * 4);
    int* csr_src = (int*)alloc((N_EDGES + N_NODES) * 4);
    float* csr_w = (float*)alloc((N_EDGES + N_NODES) * 4);
    float* WT = (float*)alloc(2 * 65536 * 4);  // WihT1, WihT2
    float* state = (float*)alloc(NB * 256 * 4);
    const size_t ACT = (size_t)T_STEPS * N_NODES * H_G;
    float* h_buf = (float*)alloc(ACT * 4);               // GCN ping
    float* hw_buf = (float*)alloc(ACT * 4);              // GCN pong / H1
    float* P_buf = (float*)alloc((size_t)CHUNK * NB * G4 * 4);  // 25 MB chunk
    float* hlast = (float*)alloc((size_t)N_NODES * H_L * 4);

    float* WihT1 = WT;
    float* WihT2 = WT + 65536;

    hipMemsetAsync(deg, 0, N_NODES * 4 * 2, stream);  // deg + cnt

    const int EB = (N_EDGES + N_NODES + 255) / 256;
    k_deg_cnt<<<EB, 256, 0, stream>>>(erow, ecol, ew, deg, cnt);
    k_dinv<<<(N_NODES + 255) / 256, 256, 0, stream>>>(deg, dinv);
    k_scan<<<1, 1024, 0, stream>>>(cnt, row_ptr);
    k_scatter<<<EB, 256, 0, stream>>>(erow, ecol, ew, dinv, cnt, csr_src, csr_w);
    k_transpose2<<<512, 256, 0, stream>>>(Wih1, Wih2, WT);

    const int MB = (T_STEPS * N_NODES) / 64;  // 768
    k_gemm<F_INP><<<MB, 256, 0, stream>>>(x, W1, hw_buf);
    k_agg<<<dim3(N_NODES / 8, T_STEPS), 256, 0, stream>>>(hw_buf, row_ptr, csr_src, csr_w, b1, h_buf);
    k_gemm<H_G><<<MB, 256, 0, stream>>>(h_buf, W2, hw_buf);
    k_agg<<<dim3(N_NODES / 8, T_STEPS), 256, 0, stream>>>(hw_buf, row_ptr, csr_src, csr_w, b2, h_buf);
    k_gemm<H_G><<<MB, 256, 0, stream>>>(h_buf, W3, hw_buf);
    k_agg<<<dim3(N_NODES / 8, T_STEPS), 256, 0, stream>>>(hw_buf, row_ptr, csr_src, csr_w, b3, h_buf);
    // h_buf now holds GCN output (T, N, 128)

    const int PB = (CHUNK * NB) / 64;  // 192 blocks per chunk GEMM

    // ---- LSTM layer 1: scan over nodes, batch = 12 time-slices ----
    hipMemsetAsync(state, 0, NB * 256 * 4, stream);
    for (int cch = 0; cch < NCHUNK; cch++) {
        k_gemm_p<<<PB, 512, 0, stream>>>(h_buf, WihT1, bih1, bhh1, P_buf, cch * CHUNK * NB, 0);
        k_rec<<<NB, 256, 0, stream>>>(P_buf, Whh1, state, hw_buf, cch * CHUNK, 0);
    }
    // hw_buf now holds H1 in scan-row order (n*12+b, 128)

    // ---- LSTM layer 2 ----
    hipMemsetAsync(state, 0, NB * 256 * 4, stream);
    for (int cch = 0; cch < NCHUNK; cch++) {
        k_gemm_p<<<PB, 512, 0, stream>>>(hw_buf, WihT2, bih2, bhh2, P_buf, cch * CHUNK * NB, 1);
        k_rec<<<NB, 256, 0, stream>>>(P_buf, Whh2, state, hlast, cch * CHUNK, 1);
    }

    k_fc<<<(N_NODES * 16) / 256, 256, 0, stream>>>(hlast, Wfc, bfc, out);
}

// Round 4
// 7259.529 us; speedup vs baseline: 1.7481x; 1.7481x over previous
//
#include <hip/hip_runtime.h>
#include <cstdint>
#include <cstddef>

// Problem constants
#define T_STEPS 12
#define N_NODES 4096
#define F_INP   64
#define H_G     128
#define H_L     128
#define N_CLS   10
#define N_EDGES 65536
#define NSEQ    N_NODES          // LSTM scan length (over nodes!)
#define NB      T_STEPS          // LSTM batch (the 12 time slices)
#define G4      (4 * H_L)        // 512 gate columns
#define CHUNK   1024             // scan steps per chunk
#define NCHUNK  (NSEQ / CHUNK)

typedef float v2f __attribute__((ext_vector_type(2)));

__device__ __forceinline__ float sigmoidf_(float x) { return 1.0f / (1.0f + expf(-x)); }
// fast sigmoid: v_exp_f32 (exp2) + v_rcp_f32; validated round 3 (absmax 2.38e-7)
__device__ __forceinline__ float fsigmoid_(float x) {
    float e = __builtin_amdgcn_exp2f(-1.44269504f * x);
    return __builtin_amdgcn_rcpf(1.0f + e);
}
__device__ __forceinline__ float geluf_(float x) { return 0.5f * x * (1.0f + erff(x * 0.70710678f)); }

// ---------------- graph preprocessing ----------------

__global__ void k_deg_cnt(const int* __restrict__ row, const int* __restrict__ col,
                          const float* __restrict__ w,
                          float* __restrict__ deg, int* __restrict__ cnt) {
    int i = blockIdx.x * 256 + threadIdx.x;
    if (i < N_EDGES) {
        int d = col[i];
        atomicAdd(&deg[d], w[i]);
        atomicAdd(&cnt[d], 1);
    } else if (i < N_EDGES + N_NODES) {
        int n = i - N_EDGES;
        atomicAdd(&deg[n], 1.0f);
        atomicAdd(&cnt[n], 1);
    }
}

__global__ void k_dinv(const float* __restrict__ deg, float* __restrict__ dinv) {
    int n = blockIdx.x * 256 + threadIdx.x;
    if (n < N_NODES) {
        float d = deg[n];
        dinv[n] = d > 0.0f ? rsqrtf(d) : 0.0f;
    }
}

__global__ void k_scan(int* cnt, int* __restrict__ row_ptr) {
    __shared__ int s[1024];
    int tid = threadIdx.x;
    int4 v = ((const int4*)cnt)[tid];
    int local = v.x + v.y + v.z + v.w;
    s[tid] = local;
    __syncthreads();
    for (int off = 1; off < 1024; off <<= 1) {
        int val = (tid >= off) ? s[tid - off] : 0;
        __syncthreads();
        s[tid] += val;
        __syncthreads();
    }
    int base = s[tid] - local;
    int4 o;
    o.x = base;
    o.y = o.x + v.x;
    o.z = o.y + v.y;
    o.w = o.z + v.z;
    ((int4*)row_ptr)[tid] = o;
    ((int4*)cnt)[tid] = o;
    if (tid == 1023) row_ptr[4096] = base + local;
}

__global__ void k_scatter(const int* __restrict__ row, const int* __restrict__ col,
                          const float* __restrict__ w, const float* __restrict__ dinv,
                          int* cursor, int* __restrict__ csr_src, float* __restrict__ csr_w) {
    int i = blockIdx.x * 256 + threadIdx.x;
    if (i < N_EDGES) {
        int d = col[i], sy = row[i];
        int pos = atomicAdd(&cursor[d], 1);
        csr_src[pos] = sy;
        csr_w[pos] = dinv[sy] * w[i] * dinv[d];
    } else if (i < N_EDGES + N_NODES) {
        int n = i - N_EDGES;
        int pos = atomicAdd(&cursor[n], 1);
        csr_src[pos] = n;
        float dv = dinv[n];
        csr_w[pos] = dv * dv;
    }
}

// transpose 2x (512,128) -> (128,512): WihT for both LSTM layers
__global__ void k_transpose2(const float* __restrict__ A0, const float* __restrict__ A1,
                             float* __restrict__ out) {
    int i = blockIdx.x * 256 + threadIdx.x;  // 0 .. 131071
    int m = i >> 16;
    int r = i & 65535;
    int k = r >> 9;
    int j = r & 511;
    const float* A = m ? A1 : A0;
    out[m * 65536 + k * 512 + j] = A[j * 128 + k];
}

// ---------------- fp32 GEMM: C[M,128] = A[M,K] @ B[K,128]  (GCN) ----------------
template <int K>
__global__ __launch_bounds__(256) void k_gemm(const float* __restrict__ A,
                                              const float* __restrict__ B,
                                              float* __restrict__ C) {
    constexpr int KP = K + 4;
    __shared__ float sA[64 * KP];
    int tid = threadIdx.x;
    size_t m0 = (size_t)blockIdx.x * 64;
    constexpr int KC = K / 4;
    for (int task = tid; task < 64 * KC; task += 256) {
        int rr = task / KC, kc = task - rr * KC;
        float4 v = *(const float4*)(A + (m0 + rr) * K + kc * 4);
        *(float4*)&sA[rr * KP + kc * 4] = v;
    }
    __syncthreads();
    int tn = tid & 31;
    int tm = tid >> 5;
    float acc[8][4];
#pragma unroll
    for (int r = 0; r < 8; r++)
#pragma unroll
        for (int j = 0; j < 4; j++) acc[r][j] = 0.0f;

    for (int k = 0; k < K; k += 4) {
        float4 b0 = *(const float4*)(B + (size_t)(k + 0) * H_G + tn * 4);
        float4 b1 = *(const float4*)(B + (size_t)(k + 1) * H_G + tn * 4);
        float4 b2 = *(const float4*)(B + (size_t)(k + 2) * H_G + tn * 4);
        float4 b3 = *(const float4*)(B + (size_t)(k + 3) * H_G + tn * 4);
#pragma unroll
        for (int r = 0; r < 8; r++) {
            float4 a = *(const float4*)&sA[(tm * 8 + r) * KP + k];
            acc[r][0] += a.x * b0.x + a.y * b1.x + a.z * b2.x + a.w * b3.x;
            acc[r][1] += a.x * b0.y + a.y * b1.y + a.z * b2.y + a.w * b3.y;
            acc[r][2] += a.x * b0.z + a.y * b1.z + a.z * b2.z + a.w * b3.z;
            acc[r][3] += a.x * b0.w + a.y * b1.w + a.z * b2.w + a.w * b3.w;
        }
    }
#pragma unroll
    for (int r = 0; r < 8; r++) {
        float4 st = make_float4(acc[r][0], acc[r][1], acc[r][2], acc[r][3]);
        *(float4*)(C + (m0 + tm * 8 + r) * H_G + tn * 4) = st;
    }
}

// ---------------- CSR aggregation + bias + exact GELU ----------------
__global__ __launch_bounds__(256) void k_agg(const float* __restrict__ hw,
                                             const int* __restrict__ row_ptr,
                                             const int* __restrict__ csr_src,
                                             const float* __restrict__ csr_w,
                                             const float* __restrict__ bias,
                                             float* __restrict__ out) {
    int f4 = threadIdx.x & 31;
    int nsub = threadIdx.x >> 5;
    int n = blockIdx.x * 8 + nsub;
    int t = blockIdx.y;
    const float* base = hw + (size_t)t * N_NODES * H_G;
    float4 acc = make_float4(0.f, 0.f, 0.f, 0.f);
    int e0 = row_ptr[n], e1 = row_ptr[n + 1];
    for (int e = e0; e < e1; e++) {
        int s = csr_src[e];
        float wv = csr_w[e];
        float4 v = *(const float4*)(base + (size_t)s * H_G + f4 * 4);
        acc.x += wv * v.x;
        acc.y += wv * v.y;
        acc.z += wv * v.z;
        acc.w += wv * v.w;
    }
    float4 b = *(const float4*)(bias + f4 * 4);
    float4 o;
    o.x = geluf_(acc.x + b.x);
    o.y = geluf_(acc.y + b.y);
    o.z = geluf_(acc.z + b.z);
    o.w = geluf_(acc.w + b.w);
    *(float4*)(out + ((size_t)t * N_NODES + n) * H_G + f4 * 4) = o;
}

// ---------------- P = x_seq @ WihT + (bih+bhh), one chunk of scan rows ----------------
__global__ __launch_bounds__(512) void k_gemm_p(const float* __restrict__ A,
                                                const float* __restrict__ BT,
                                                const float* __restrict__ bih,
                                                const float* __restrict__ bhh,
                                                float* __restrict__ Pout,
                                                int r_base, int mode) {
    __shared__ float sA[64 * 128];
    int tid = threadIdx.x;
    int r0 = r_base + blockIdx.x * 64;
    for (int task = tid; task < 64 * 32; task += 512) {
        int rr = task >> 5, kc = task & 31;
        int r = r0 + rr;
        int arow = (mode == 0) ? ((r % 12) * N_NODES + r / 12) : r;
        *(float4*)&sA[rr * 128 + kc * 4] = *(const float4*)(A + (size_t)arow * 128 + kc * 4);
    }
    __syncthreads();
    int jc = tid & 127;
    int rg = tid >> 7;
    float acc[16][4];
#pragma unroll
    for (int rr = 0; rr < 16; rr++)
#pragma unroll
        for (int j = 0; j < 4; j++) acc[rr][j] = 0.f;

    for (int k = 0; k < 128; k += 4) {
        float4 b0 = *(const float4*)(BT + (size_t)(k + 0) * G4 + jc * 4);
        float4 b1 = *(const float4*)(BT + (size_t)(k + 1) * G4 + jc * 4);
        float4 b2 = *(const float4*)(BT + (size_t)(k + 2) * G4 + jc * 4);
        float4 b3 = *(const float4*)(BT + (size_t)(k + 3) * G4 + jc * 4);
#pragma unroll
        for (int rr = 0; rr < 16; rr++) {
            float4 a = *(const float4*)&sA[(rg * 16 + rr) * 128 + k];
            acc[rr][0] += a.x * b0.x + a.y * b1.x + a.z * b2.x + a.w * b3.x;
            acc[rr][1] += a.x * b0.y + a.y * b1.y + a.z * b2.y + a.w * b3.y;
            acc[rr][2] += a.x * b0.z + a.y * b1.z + a.z * b2.z + a.w * b3.z;
            acc[rr][3] += a.x * b0.w + a.y * b1.w + a.z * b2.w + a.w * b3.w;
        }
    }
    float bx = bih[jc * 4 + 0] + bhh[jc * 4 + 0];
    float by = bih[jc * 4 + 1] + bhh[jc * 4 + 1];
    float bz = bih[jc * 4 + 2] + bhh[jc * 4 + 2];
    float bw = bih[jc * 4 + 3] + bhh[jc * 4 + 3];
#pragma unroll
    for (int rr = 0; rr < 16; rr++) {
        int lrow = r0 - r_base + rg * 16 + rr;
        float4 st = make_float4(acc[rr][0] + bx, acc[rr][1] + by, acc[rr][2] + bz, acc[rr][3] + bw);
        *(float4*)(Pout + (size_t)lrow * G4 + jc * 4) = st;
    }
}

// ---------------- sequential LSTM recurrence over one chunk ----------------
// 12 blocks (one per batch element b). 512 threads (8 waves/CU, 2/SIMD via
// __launch_bounds__(512,2) -> VGPR budget 256). Thread j owns gate column j.
// CRITICAL: the 128 Whh weights are held in 64 INDIVIDUALLY-NAMED v2f registers
// (no array -> no SROA failure -> no scratch spill; rounds 2/3 streamed weights
// from L2/scratch every step because the compiler demoted weight arrays).
// h broadcast from LDS via 32 ds_read_b128/thread; dot via v_pk_fma_f32.

#define WDECL8(a,b,c,d,e,f,g,h) \
    v2f w##a = wp[a], w##b = wp[b], w##c = wp[c], w##d = wp[d], \
        w##e = wp[e], w##f = wp[f], w##g = wp[g], w##h = wp[h];

// one float4 broadcast read feeds two pk-fmas on two accumulators
#define WFMA2(q, wa, wb, aa, ab) { \
    float4 h4 = *(const float4*)&sh[4*(q)]; \
    v2f hlo; hlo.x = h4.x; hlo.y = h4.y; \
    v2f hhi; hhi.x = h4.z; hhi.y = h4.w; \
    aa += wa * hlo; ab += wb * hhi; }

__global__ __launch_bounds__(512, 2) void k_rec(const float* __restrict__ P,
                                                const float* __restrict__ Whh,
                                                float* __restrict__ state,
                                                float* __restrict__ Hout,
                                                int n0, int wmode) {
    __shared__ float sh[H_L];     // h_prev
    __shared__ float gact[G4];    // activated gates
    int j = threadIdx.x;
    int b = blockIdx.x;

    const v2f* wp = (const v2f*)(Whh + (size_t)j * 128);
    WDECL8(0,1,2,3,4,5,6,7)
    WDECL8(8,9,10,11,12,13,14,15)
    WDECL8(16,17,18,19,20,21,22,23)
    WDECL8(24,25,26,27,28,29,30,31)
    WDECL8(32,33,34,35,36,37,38,39)
    WDECL8(40,41,42,43,44,45,46,47)
    WDECL8(48,49,50,51,52,53,54,55)
    WDECL8(56,57,58,59,60,61,62,63)

    float c = 0.f;
    if (j < H_L) {
        sh[j] = state[b * 256 + j];
        c = state[b * 256 + 128 + j];
    }
    float pnext = P[(size_t)b * G4 + j];  // prefetch step 0
    __syncthreads();

    int gtype = j >> 7;  // 0:i 1:f 2:g 3:o

    for (int i = 0; i < CHUNK; i++) {
        float p = pnext;
        int inx = (i + 1 < CHUNK) ? (i + 1) : i;
        pnext = P[((size_t)inx * NB + b) * G4 + j];

        v2f a0; a0.x = 0.f; a0.y = 0.f;
        v2f a1 = a0, a2 = a0, a3 = a0;
        WFMA2(0,  w0,  w1,  a0, a1)
        WFMA2(1,  w2,  w3,  a2, a3)
        WFMA2(2,  w4,  w5,  a0, a1)
        WFMA2(3,  w6,  w7,  a2, a3)
        WFMA2(4,  w8,  w9,  a0, a1)
        WFMA2(5,  w10, w11, a2, a3)
        WFMA2(6,  w12, w13, a0, a1)
        WFMA2(7,  w14, w15, a2, a3)
        WFMA2(8,  w16, w17, a0, a1)
        WFMA2(9,  w18, w19, a2, a3)
        WFMA2(10, w20, w21, a0, a1)
        WFMA2(11, w22, w23, a2, a3)
        WFMA2(12, w24, w25, a0, a1)
        WFMA2(13, w26, w27, a2, a3)
        WFMA2(14, w28, w29, a0, a1)
        WFMA2(15, w30, w31, a2, a3)
        WFMA2(16, w32, w33, a0, a1)
        WFMA2(17, w34, w35, a2, a3)
        WFMA2(18, w36, w37, a0, a1)
        WFMA2(19, w38, w39, a2, a3)
        WFMA2(20, w40, w41, a0, a1)
        WFMA2(21, w42, w43, a2, a3)
        WFMA2(22, w44, w45, a0, a1)
        WFMA2(23, w46, w47, a2, a3)
        WFMA2(24, w48, w49, a0, a1)
        WFMA2(25, w50, w51, a2, a3)
        WFMA2(26, w52, w53, a0, a1)
        WFMA2(27, w54, w55, a2, a3)
        WFMA2(28, w56, w57, a0, a1)
        WFMA2(29, w58, w59, a2, a3)
        WFMA2(30, w60, w61, a0, a1)
        WFMA2(31, w62, w63, a2, a3)
        v2f s01 = a0 + a1;
        v2f s23 = a2 + a3;
        v2f s = s01 + s23;
        float g = p + s.x + s.y;

        gact[j] = (gtype == 2) ? tanhf(g) : fsigmoid_(g);
        __syncthreads();

        if (j < H_L) {
            c = gact[H_L + j] * c + gact[j] * gact[2 * H_L + j];
            float hval = gact[3 * H_L + j] * tanhf(c);
            sh[j] = hval;
            if (wmode == 0)
                Hout[((size_t)(n0 + i) * NB + b) * H_L + j] = hval;
            else if (b == NB - 1)
                Hout[(size_t)(n0 + i) * H_L + j] = hval;
        }
        __syncthreads();
    }

    if (j < H_L) {
        state[b * 256 + j] = sh[j];
        state[b * 256 + 128 + j] = c;
    }
}

// ---------------- final FC: out[n,c] = hlast[n,:] . Wfc[c,:] + bfc[c] ----------------
__global__ __launch_bounds__(256) void k_fc(const float* __restrict__ Hlast,
                                            const float* __restrict__ Wfc,
                                            const float* __restrict__ bfc,
                                            float* __restrict__ out) {
    int flat = blockIdx.x * 256 + threadIdx.x;
    int n = flat >> 4, cc = flat & 15;
    if (cc < N_CLS) {
        const float* h = Hlast + (size_t)n * H_L;
        const float* wr = Wfc + (size_t)cc * H_L;
        float acc = bfc[cc];
        for (int k = 0; k < 128; k += 4) {
            float4 hvv = *(const float4*)(h + k);
            float4 wv = *(const float4*)(wr + k);
            acc += hvv.x * wv.x + hvv.y * wv.y + hvv.z * wv.z + hvv.w * wv.w;
        }
        out[n * N_CLS + cc] = acc;
    }
}

extern "C" void kernel_launch(void* const* d_in, const int* in_sizes, int n_in,
                              void* d_out, int out_size, void* d_ws, size_t ws_size,
                              hipStream_t stream) {
    const float* x = (const float*)d_in[0];
    const int* eidx = (const int*)d_in[1];
    const int* erow = eidx;
    const int* ecol = eidx + N_EDGES;
    const float* ew = (const float*)d_in[2];
    const float* W1 = (const float*)d_in[3];
    const float* b1 = (const float*)d_in[4];
    const float* W2 = (const float*)d_in[5];
    const float* b2 = (const float*)d_in[6];
    const float* W3 = (const float*)d_in[7];
    const float* b3 = (const float*)d_in[8];
    const float* Wih1 = (const float*)d_in[9];
    const float* Whh1 = (const float*)d_in[10];
    const float* bih1 = (const float*)d_in[11];
    const float* bhh1 = (const float*)d_in[12];
    const float* Wih2 = (const float*)d_in[13];
    const float* Whh2 = (const float*)d_in[14];
    const float* bih2 = (const float*)d_in[15];
    const float* bhh2 = (const float*)d_in[16];
    const float* Wfc = (const float*)d_in[17];
    const float* bfc = (const float*)d_in[18];
    float* out = (float*)d_out;

    char* p = (char*)d_ws;
    auto alloc = [&](size_t bytes) -> char* {
        char* r = p;
        p += (bytes + 255) & ~(size_t)255;
        return r;
    };
    float* deg = (float*)alloc(N_NODES * 4);  // adjacent to cnt (single memset)
    int* cnt = (int*)alloc(N_NODES * 4);
    float* dinv = (float*)alloc(N_NODES * 4);
    int* row_ptr = (int*)alloc((N_NODES + 1) * 4);
    int* csr_src = (int*)alloc((N_EDGES + N_NODES) * 4);
    float* csr_w = (float*)alloc((N_EDGES + N_NODES) * 4);
    float* WT = (float*)alloc(2 * 65536 * 4);  // WihT1, WihT2
    float* state = (float*)alloc(NB * 256 * 4);
    const size_t ACT = (size_t)T_STEPS * N_NODES * H_G;
    float* h_buf = (float*)alloc(ACT * 4);               // GCN ping
    float* hw_buf = (float*)alloc(ACT * 4);              // GCN pong / H1
    float* P_buf = (float*)alloc((size_t)CHUNK * NB * G4 * 4);  // 25 MB chunk
    float* hlast = (float*)alloc((size_t)N_NODES * H_L * 4);

    float* WihT1 = WT;
    float* WihT2 = WT + 65536;

    hipMemsetAsync(deg, 0, N_NODES * 4 * 2, stream);  // deg + cnt

    const int EB = (N_EDGES + N_NODES + 255) / 256;
    k_deg_cnt<<<EB, 256, 0, stream>>>(erow, ecol, ew, deg, cnt);
    k_dinv<<<(N_NODES + 255) / 256, 256, 0, stream>>>(deg, dinv);
    k_scan<<<1, 1024, 0, stream>>>(cnt, row_ptr);
    k_scatter<<<EB, 256, 0, stream>>>(erow, ecol, ew, dinv, cnt, csr_src, csr_w);
    k_transpose2<<<512, 256, 0, stream>>>(Wih1, Wih2, WT);

    const int MB = (T_STEPS * N_NODES) / 64;  // 768
    k_gemm<F_INP><<<MB, 256, 0, stream>>>(x, W1, hw_buf);
    k_agg<<<dim3(N_NODES / 8, T_STEPS), 256, 0, stream>>>(hw_buf, row_ptr, csr_src, csr_w, b1, h_buf);
    k_gemm<H_G><<<MB, 256, 0, stream>>>(h_buf, W2, hw_buf);
    k_agg<<<dim3(N_NODES / 8, T_STEPS), 256, 0, stream>>>(hw_buf, row_ptr, csr_src, csr_w, b2, h_buf);
    k_gemm<H_G><<<MB, 256, 0, stream>>>(h_buf, W3, hw_buf);
    k_agg<<<dim3(N_NODES / 8, T_STEPS), 256, 0, stream>>>(hw_buf, row_ptr, csr_src, csr_w, b3, h_buf);
    // h_buf now holds GCN output (T, N, 128)

    const int PB = (CHUNK * NB) / 64;  // 192 blocks per chunk GEMM

    // ---- LSTM layer 1: scan over nodes, batch = 12 time-slices ----
    hipMemsetAsync(state, 0, NB * 256 * 4, stream);
    for (int cch = 0; cch < NCHUNK; cch++) {
        k_gemm_p<<<PB, 512, 0, stream>>>(h_buf, WihT1, bih1, bhh1, P_buf, cch * CHUNK * NB, 0);
        k_rec<<<NB, 512, 0, stream>>>(P_buf, Whh1, state, hw_buf, cch * CHUNK, 0);
    }
    // hw_buf now holds H1 in scan-row order (n*12+b, 128)

    // ---- LSTM layer 2 ----
    hipMemsetAsync(state, 0, NB * 256 * 4, stream);
    for (int cch = 0; cch < NCHUNK; cch++) {
        k_gemm_p<<<PB, 512, 0, stream>>>(hw_buf, WihT2, bih2, bhh2, P_buf, cch * CHUNK * NB, 1);
        k_rec<<<NB, 512, 0, stream>>>(P_buf, Whh2, state, hlast, cch * CHUNK, 1);
    }

    k_fc<<<(N_NODES * 16) / 256, 256, 0, stream>>>(hlast, Wfc, bfc, out);
}